// Round 13
// baseline (2766.818 us; speedup 1.0000x reference)
//
#include <hip/hip_runtime.h>
#include <stdint.h>

#define BATCH 128
#define SEQL  512
#define FDIM  768
#define CTAGS 52
#define START_IDX 50
#define STOP_IDX  51
#define NEG_INF (-3.0e38f)

// ---------------------------------------------------------------------------
// K1: emission GEMM v8 — W via LDS broadcast (scalar pipe retired).
// Block = 64 rows (lane=row) x 4 waves (13 cols each). W staged per 64-k
// chunk into LDS transposed [c][k] (coalesced float4 copies straight from
// row-major W — no wtrans kernel), double-buffered, ONE barrier per chunk.
// Per 4-k SUB: 13 uniform-address ds_read_b128 (HW broadcast) feed 52 FMAs
// (1:4 on the DS pipe). F streams per-lane global dwordx4 as in gemm6.
// ---------------------------------------------------------------------------
#define KCH 64
#define WQ  (KCH * CTAGS / 4)   // 832 float4 per W chunk

__global__ __launch_bounds__(256) void emit_gemm8(
    const float* __restrict__ F, const float* __restrict__ W,
    const float* __restrict__ bias, float* __restrict__ emit)
{
    __shared__ float wbuf[2][CTAGS * KCH];   // [c][k] chunks, 2 x 13312 B

    const int tid  = threadIdx.x;
    const int lane = tid & 63;
    const int cg   = __builtin_amdgcn_readfirstlane(tid >> 6);
    const int c0   = cg * 13;
    const int row  = blockIdx.x * 64 + lane;

    const float* fp = F + (size_t)row * FDIM;

    float acc[13];
#pragma unroll
    for (int c = 0; c < 13; ++c) acc[c] = bias[c0 + c];

    // stage W chunk 0: LDS[c][k] = W[c][k], 16 float4 per c-row
    for (int i = tid; i < WQ; i += 256) {
        int c  = i >> 4;
        int kq = i & 15;
        *(float4*)&wbuf[0][c * KCH + kq * 4] =
            *(const float4*)&W[(size_t)c * FDIM + kq * 4];
    }
    __syncthreads();

    // F prologue: first 16-k supergroup
    float4 fA = *(const float4*)(fp + 0);
    float4 fB = *(const float4*)(fp + 4);
    float4 fC = *(const float4*)(fp + 8);
    float4 fD = *(const float4*)(fp + 12);

    // 4-k SUB: 13 uniform b128 reads from LDS, 52 FMAs
#define SUBL(wb, fq, kl)                                                     \
    {                                                                        \
        _Pragma("unroll")                                                    \
        for (int c = 0; c < 13; ++c) {                                       \
            float4 w = *(const float4*)&wb[(c0 + c) * KCH + (kl)];           \
            acc[c] = fmaf(fq.x, w.x, acc[c]);                                \
            acc[c] = fmaf(fq.y, w.y, acc[c]);                                \
            acc[c] = fmaf(fq.z, w.z, acc[c]);                                \
            acc[c] = fmaf(fq.w, w.w, acc[c]);                                \
        }                                                                    \
    }

    for (int ch = 0; ch < FDIM / KCH; ++ch) {
        const int kb   = ch * KCH;
        const int more = (ch + 1 < FDIM / KCH);

        // issue next W chunk's global loads NOW (consumed after compute)
        float4 s0, s1, s2, s3;
        if (more) {
            const float* wsrc = W + (size_t)(ch + 1) * KCH;
            int i;
            i = tid;        s0 = *(const float4*)&wsrc[(size_t)(i >> 4) * FDIM + (i & 15) * 4];
            i = tid + 256;  s1 = *(const float4*)&wsrc[(size_t)(i >> 4) * FDIM + (i & 15) * 4];
            i = tid + 512;  s2 = *(const float4*)&wsrc[(size_t)(i >> 4) * FDIM + (i & 15) * 4];
            i = tid + 768;
            if (i < WQ)     s3 = *(const float4*)&wsrc[(size_t)(i >> 4) * FDIM + (i & 15) * 4];
        }

        const float* wb = wbuf[ch & 1];

#pragma unroll
        for (int sg = 0; sg < KCH / 16; ++sg) {
            const int k0 = kb + sg * 16;

            // prefetch next F supergroup (vmcnt pipe)
            float4 nA, nB, nC, nD;
            if (k0 + 16 < FDIM) {
                nA = *(const float4*)(fp + k0 + 16);
                nB = *(const float4*)(fp + k0 + 20);
                nC = *(const float4*)(fp + k0 + 24);
                nD = *(const float4*)(fp + k0 + 28);
            }

            const int kl = sg * 16;
            SUBL(wb, fA, kl + 0)
            SUBL(wb, fB, kl + 4)
            SUBL(wb, fC, kl + 8)
            SUBL(wb, fD, kl + 12)

            fA = nA; fB = nB; fC = nC; fD = nD;
        }

        // write staged chunk to the other buffer; one barrier per chunk.
        // Safe: buffer (ch+1)&1 was last READ in chunk ch-1, which all waves
        // finished before the barrier at the end of chunk ch-1.
        if (more) {
            float* nb = wbuf[(ch + 1) & 1];
            int i;
            i = tid;        *(float4*)&nb[(i >> 4) * KCH + (i & 15) * 4] = s0;
            i = tid + 256;  *(float4*)&nb[(i >> 4) * KCH + (i & 15) * 4] = s1;
            i = tid + 512;  *(float4*)&nb[(i >> 4) * KCH + (i & 15) * 4] = s2;
            i = tid + 768;
            if (i < WQ)     *(float4*)&nb[(i >> 4) * KCH + (i & 15) * 4] = s3;
        }
        __syncthreads();
    }
#undef SUBL

    float* eo = emit + (size_t)row * CTAGS + c0;
#pragma unroll
    for (int c = 0; c < 13; ++c) eo[c] = acc[c];
}

// ---------------------------------------------------------------------------
// K2: serial Viterbi scan (R7 champion, byte-identical logic).
// ---------------------------------------------------------------------------
#define CHUNK 32
#define CQ   (CHUNK * CTAGS / 4)   // float4s per chunk = 416

__global__ __launch_bounds__(64) void viterbi_scan(
    const float* __restrict__ emit, const int* __restrict__ masks,
    const float* __restrict__ T, float* __restrict__ s_hist,
    float* __restrict__ out, int* __restrict__ btag)
{
    const int b  = blockIdx.x;
    const int to = threadIdx.x;
    const int toc = (to < CTAGS) ? to : (CTAGS - 1);

    __shared__ float ebuf[2][CHUNK * CTAGS];     // 2 x 6656 B
    __shared__ int   ml[SEQL];                   // 2 KB
    __shared__ __align__(16) float st[64];       // state vector (52 used)

    const float4* Tq = (const float4*)(T + (size_t)toc * CTAGS);
    const float4 tr0 = Tq[0],  tr1 = Tq[1],  tr2 = Tq[2],  tr3 = Tq[3];
    const float4 tr4 = Tq[4],  tr5 = Tq[5],  tr6 = Tq[6],  tr7 = Tq[7];
    const float4 tr8 = Tq[8],  tr9 = Tq[9],  tr10 = Tq[10], tr11 = Tq[11];
    const float4 tr12 = Tq[12];
    const float tstop = T[STOP_IDX * CTAGS + toc];

    const float*  eb  = emit   + (size_t)b * SEQL * CTAGS;
    const float4* ebq = (const float4*)eb;
    const int*    mb  = masks  + (size_t)b * SEQL;
    float*        sb  = s_hist + (size_t)b * SEQL * CTAGS;

#pragma unroll
    for (int j = 0; j < 8; ++j) ml[to + 64 * j] = mb[to + 64 * j];
#pragma unroll
    for (int j = 0; j < 7; ++j) {
        int idx = to + 64 * j;
        if (idx < CQ) *(float4*)&ebuf[0][idx * 4] = ebq[idx];
    }
    st[to] = (to == START_IDX) ? 0.f : -10000.f;

    float cur   = (to == START_IDX) ? 0.f : -10000.f;
    float e_cur = ebuf[0][toc];
    int   m_cur = ml[0];
    int   cb    = 0;

    for (int c = 0; c < SEQL / CHUNK; ++c) {
        float4 p0, p1, p2, p3, p4, p5, p6;
        const int more = (c < SEQL / CHUNK - 1);
        if (more) {
            const float4* src = ebq + (size_t)(c + 1) * CQ;
            p0 = src[to];
            p1 = src[to + 64];
            p2 = src[to + 128];
            p3 = src[to + 192];
            p4 = src[to + 256];
            p5 = src[to + 320];
            if (to < CQ - 384) p6 = src[to + 384];
        }

        for (int s = 0; s < CHUNK; ++s) {
            const int t = c * CHUNK + s;

            float e_nxt = 0.f;
            if (s < CHUNK - 1) e_nxt = ebuf[cb][(s + 1) * CTAGS + toc];
            int m_nxt = (t + 1 < SEQL) ? ml[t + 1] : 0;

            if (to < CTAGS) sb[(size_t)t * CTAGS + to] = cur;

            const float4 s0q  = *(const float4*)&st[0];
            const float4 s1q  = *(const float4*)&st[4];
            const float4 s2q  = *(const float4*)&st[8];
            const float4 s3q  = *(const float4*)&st[12];
            const float4 s4q  = *(const float4*)&st[16];
            const float4 s5q  = *(const float4*)&st[20];
            const float4 s6q  = *(const float4*)&st[24];
            const float4 s7q  = *(const float4*)&st[28];
            const float4 s8q  = *(const float4*)&st[32];
            const float4 s9q  = *(const float4*)&st[36];
            const float4 s10q = *(const float4*)&st[40];
            const float4 s11q = *(const float4*)&st[44];
            const float4 s12q = *(const float4*)&st[48];

            float a[CTAGS];
#define ADQ(q, sq, trq)                                                      \
            a[4*q+0] = sq.x + trq.x;  a[4*q+1] = sq.y + trq.y;               \
            a[4*q+2] = sq.z + trq.z;  a[4*q+3] = sq.w + trq.w;
            ADQ(0, s0q, tr0)   ADQ(1, s1q, tr1)   ADQ(2, s2q, tr2)
            ADQ(3, s3q, tr3)   ADQ(4, s4q, tr4)   ADQ(5, s5q, tr5)
            ADQ(6, s6q, tr6)   ADQ(7, s7q, tr7)   ADQ(8, s8q, tr8)
            ADQ(9, s9q, tr9)   ADQ(10, s10q, tr10) ADQ(11, s11q, tr11)
            ADQ(12, s12q, tr12)
#undef ADQ

            float l1[17];
#pragma unroll
            for (int i = 0; i < 17; ++i)
                l1[i] = fmaxf(fmaxf(a[3 * i], a[3 * i + 1]), a[3 * i + 2]);
            float l2[6];
#pragma unroll
            for (int i = 0; i < 5; ++i)
                l2[i] = fmaxf(fmaxf(l1[3 * i], l1[3 * i + 1]), l1[3 * i + 2]);
            l2[5] = fmaxf(fmaxf(l1[15], l1[16]), a[51]);
            const float m = fmaxf(fmaxf(fmaxf(l2[0], l2[1]), l2[2]),
                                  fmaxf(fmaxf(l2[3], l2[4]), l2[5]));

            cur = m_cur ? (m + e_cur) : cur;

            if (to < CTAGS) st[to] = cur;

            e_cur = e_nxt;
            m_cur = m_nxt;
        }

        if (more) {
            const int nb = cb ^ 1;
            *(float4*)&ebuf[nb][to * 4]         = p0;
            *(float4*)&ebuf[nb][(to + 64) * 4]  = p1;
            *(float4*)&ebuf[nb][(to + 128) * 4] = p2;
            *(float4*)&ebuf[nb][(to + 192) * 4] = p3;
            *(float4*)&ebuf[nb][(to + 256) * 4] = p4;
            *(float4*)&ebuf[nb][(to + 320) * 4] = p5;
            if (to < CQ - 384) *(float4*)&ebuf[nb][(to + 384) * 4] = p6;
            e_cur = ebuf[nb][toc];
        }
        cb ^= 1;
    }

    float v   = (to < CTAGS) ? (cur + tstop) : NEG_INF;
    int  bidx = to;
#pragma unroll
    for (int s = 1; s < 64; s <<= 1) {
        float ov = __shfl_xor(v, s);
        int   oi = __shfl_xor(bidx, s);
        if (ov > v || (ov == v && oi < bidx)) { v = ov; bidx = oi; }
    }
    if (to == 0) { out[b] = v; btag[b] = bidx; }
}

// ---------------------------------------------------------------------------
// K3: backpointers, parallel over (b,t). (unchanged, known-good)
// ---------------------------------------------------------------------------
#define PPW 16

__global__ __launch_bounds__(256) void bp_compute(
    const float* __restrict__ s_hist, const float* __restrict__ T,
    unsigned char* __restrict__ bp)
{
    const int lane = threadIdx.x & 63;
    const int wv   = __builtin_amdgcn_readfirstlane(threadIdx.x >> 6);
    const int toc  = (lane < CTAGS) ? lane : (CTAGS - 1);
    const int w    = blockIdx.x * 4 + wv;

    float Trow[CTAGS];
#pragma unroll
    for (int f = 0; f < CTAGS; ++f) Trow[f] = T[toc * CTAGS + f];

    for (int i = 0; i < PPW; ++i) {
        const int p = w * PPW + i;            // p = b*SEQL + t
        const float* sp = s_hist + (size_t)p * CTAGS;

        float a[CTAGS];
#pragma unroll
        for (int q = 0; q < 13; ++q) {
            float4 sv = *(const float4*)(sp + q * 4);
            a[q * 4 + 0] = sv.x + Trow[q * 4 + 0];
            a[q * 4 + 1] = sv.y + Trow[q * 4 + 1];
            a[q * 4 + 2] = sv.z + Trow[q * 4 + 2];
            a[q * 4 + 3] = sv.w + Trow[q * 4 + 3];
        }

        float l1[17];
#pragma unroll
        for (int j = 0; j < 17; ++j)
            l1[j] = fmaxf(fmaxf(a[3 * j], a[3 * j + 1]), a[3 * j + 2]);
        float l2[6];
#pragma unroll
        for (int j = 0; j < 5; ++j)
            l2[j] = fmaxf(fmaxf(l1[3 * j], l1[3 * j + 1]), l1[3 * j + 2]);
        l2[5] = fmaxf(fmaxf(l1[15], l1[16]), a[51]);
        const float m = fmaxf(fmaxf(fmaxf(l2[0], l2[1]), l2[2]),
                              fmaxf(fmaxf(l2[3], l2[4]), l2[5]));

        int c1[18];
#pragma unroll
        for (int j = 0; j < 17; ++j) {
            int x = (a[3 * j]     == m) ? (3 * j)     : 63;
            int y = (a[3 * j + 1] == m) ? (3 * j + 1) : 63;
            int z = (a[3 * j + 2] == m) ? (3 * j + 2) : 63;
            c1[j] = min(min(x, y), z);
        }
        c1[17] = (a[51] == m) ? 51 : 63;
        int c2[6];
#pragma unroll
        for (int j = 0; j < 6; ++j)
            c2[j] = min(min(c1[3 * j], c1[3 * j + 1]), c1[3 * j + 2]);
        const int idx = min(min(min(c2[0], c2[1]), c2[2]),
                            min(min(c2[3], c2[4]), c2[5]));

        if (lane < CTAGS)
            bp[(size_t)p * CTAGS + lane] = (unsigned char)idx;
    }
}

// ---------------------------------------------------------------------------
// K4: backtrack (unchanged, known-good).
// ---------------------------------------------------------------------------
__global__ __launch_bounds__(64) void viterbi_bt(
    const unsigned char* __restrict__ bp, const int* __restrict__ masks,
    const int* __restrict__ btag, float* __restrict__ out)
{
    const int b   = blockIdx.x;
    const int tid = threadIdx.x;

    __shared__ __align__(16) unsigned char bpl[SEQL * CTAGS];
    __shared__ int ml[SEQL];
    __shared__ unsigned char pathb[SEQL];

    const uint4* src = (const uint4*)(bp + (size_t)b * SEQL * CTAGS);
    for (int i = tid; i < SEQL * CTAGS / 16; i += 64)
        ((uint4*)bpl)[i] = src[i];
    for (int i = tid; i < SEQL; i += 64) ml[i] = masks[(size_t)b * SEQL + i];
    __syncthreads();

    int c = btag[b];
    if (tid == 0) pathb[SEQL - 1] = (unsigned char)c;
    for (int i = SEQL - 2; i >= 0; --i) {
        int nxt = bpl[(i + 1) * CTAGS + c];
        c = ml[i] ? nxt : c;
        if (tid == 0) pathb[i] = (unsigned char)c;
    }
    __syncthreads();

    float* po = out + BATCH + (size_t)b * SEQL;
#pragma unroll
    for (int i = 0; i < 8; ++i)
        po[i * 64 + tid] = (float)pathb[i * 64 + tid];
}

// ---------------------------------------------------------------------------
extern "C" void kernel_launch(void* const* d_in, const int* in_sizes, int n_in,
                              void* d_out, int out_size, void* d_ws, size_t ws_size,
                              hipStream_t stream)
{
    const float* features = (const float*)d_in[0];
    const int*   masks    = (const int*)d_in[1];
    const float* W        = (const float*)d_in[2];
    const float* bias     = (const float*)d_in[3];
    const float* T        = (const float*)d_in[4];

    float* out = (float*)d_out;

    // ws layout: emit/s_hist (13.63 MB, aliased) | bp (3.41 MB) | btag
    const size_t emit_bytes = (size_t)BATCH * SEQL * CTAGS * sizeof(float);
    const size_t bp_bytes   = (size_t)BATCH * SEQL * CTAGS;
    float*         emit   = (float*)d_ws;
    float*         s_hist = emit;  // alias: scan consumes emit[t] before overwrite
    unsigned char* bpws   = (unsigned char*)d_ws + emit_bytes;
    int*           btag   = (int*)((unsigned char*)d_ws + emit_bytes + bp_bytes);

    emit_gemm8<<<BATCH * SEQL / 64, 256, 0, stream>>>(features, W, bias, emit);
    viterbi_scan<<<BATCH, 64, 0, stream>>>(emit, masks, T, s_hist, out, btag);
    bp_compute<<<BATCH * SEQL / (4 * PPW), 256, 0, stream>>>(s_hist, T, bpws);
    viterbi_bt<<<BATCH, 64, 0, stream>>>(bpws, masks, btag, out);
}

// Round 14
// 1673.336 us; speedup vs baseline: 1.6535x; 1.6535x over previous
//
#include <hip/hip_runtime.h>
#include <stdint.h>

#define BATCH 128
#define SEQL  512
#define FDIM  768
#define CTAGS 52
#define START_IDX 50
#define STOP_IDX  51
#define NEG_INF (-3.0e38f)

// ---------------------------------------------------------------------------
// K1: emission GEMM v9 — W via LDS broadcast, spill-proof staging.
// Block = 64 rows (lane=row) x 4 waves (13 cols each, c0 = 13*wave).
// Per 64-k chunk: stage next chunk's W into the other LDS buffer with
// SHORT-LIVED registers (load 4xfloat4 -> ds_write immediately; liveness
// ~10 insts — fixes gemm8's VGPR=256 spill), then compute 4 supergroups
// of 16 k: F per-lane global dwordx4 double-buffered (gemm6-proven),
// W via 13 uniform-address ds_read_b128 per 4-k (HW broadcast, 16B/inst).
// One __syncthreads per chunk. W read row-major directly (no wtrans).
// ---------------------------------------------------------------------------
#define KCH 64
#define WQ  (KCH * CTAGS / 4)   // 832 float4 per W chunk

__global__ __launch_bounds__(256) void emit_gemm9(
    const float* __restrict__ F, const float* __restrict__ W,
    const float* __restrict__ bias, float* __restrict__ emit)
{
    __shared__ float wbuf[2][CTAGS * KCH];   // [c][k] chunks, 2 x 13312 B

    const int tid  = threadIdx.x;
    const int lane = tid & 63;
    const int cg   = __builtin_amdgcn_readfirstlane(tid >> 6);
    const int c0   = cg * 13;
    const int row  = blockIdx.x * 64 + lane;

    const float* fp = F + (size_t)row * FDIM;

    float acc[13];
#pragma unroll
    for (int c = 0; c < 13; ++c) acc[c] = bias[c0 + c];

    // short-lived staging of W chunk `kb` into wbuf[which]
#define STAGE_W(which, kb)                                                   \
    {                                                                        \
        float4 v0, v1, v2, v3;                                               \
        int i0s = tid, i1s = tid + 256, i2s = tid + 512, i3s = tid + 768;    \
        v0 = *(const float4*)&W[(size_t)(i0s >> 4) * FDIM + (kb) + (i0s & 15) * 4]; \
        v1 = *(const float4*)&W[(size_t)(i1s >> 4) * FDIM + (kb) + (i1s & 15) * 4]; \
        v2 = *(const float4*)&W[(size_t)(i2s >> 4) * FDIM + (kb) + (i2s & 15) * 4]; \
        if (i3s < WQ)                                                        \
            v3 = *(const float4*)&W[(size_t)(i3s >> 4) * FDIM + (kb) + (i3s & 15) * 4]; \
        *(float4*)&wbuf[which][(i0s >> 4) * KCH + (i0s & 15) * 4] = v0;      \
        *(float4*)&wbuf[which][(i1s >> 4) * KCH + (i1s & 15) * 4] = v1;      \
        *(float4*)&wbuf[which][(i2s >> 4) * KCH + (i2s & 15) * 4] = v2;      \
        if (i3s < WQ)                                                        \
            *(float4*)&wbuf[which][(i3s >> 4) * KCH + (i3s & 15) * 4] = v3;  \
    }

    // 4-k SUB: 13 uniform-address b128 reads (broadcast), 52 FMAs
#define SUBL(wb, fq, kl)                                                     \
    {                                                                        \
        _Pragma("unroll")                                                    \
        for (int c = 0; c < 13; ++c) {                                       \
            float4 w = *(const float4*)&wb[(c0 + c) * KCH + (kl)];           \
            acc[c] = fmaf(fq.x, w.x, acc[c]);                                \
            acc[c] = fmaf(fq.y, w.y, acc[c]);                                \
            acc[c] = fmaf(fq.z, w.z, acc[c]);                                \
            acc[c] = fmaf(fq.w, w.w, acc[c]);                                \
        }                                                                    \
    }

    // prologue: stage chunk 0, load first F supergroup
    STAGE_W(0, 0)
    __syncthreads();

    float4 fA = *(const float4*)(fp + 0);
    float4 fB = *(const float4*)(fp + 4);
    float4 fC = *(const float4*)(fp + 8);
    float4 fD = *(const float4*)(fp + 12);

    for (int ch = 0; ch < FDIM / KCH; ++ch) {
        const int kb   = ch * KCH;
        const int more = (ch + 1 < FDIM / KCH);

        // stage next W chunk NOW (short liveness; latency hidden by the
        // other 3 waves/SIMD at 4 blocks/CU)
        if (more) STAGE_W((ch + 1) & 1, kb + KCH)

        const float* wb = wbuf[ch & 1];

#pragma unroll
        for (int sg = 0; sg < KCH / 16; ++sg) {
            const int k0 = kb + sg * 16;

            // prefetch next F supergroup (vmcnt pipe)
            float4 nA, nB, nC, nD;
            if (k0 + 16 < FDIM) {
                nA = *(const float4*)(fp + k0 + 16);
                nB = *(const float4*)(fp + k0 + 20);
                nC = *(const float4*)(fp + k0 + 24);
                nD = *(const float4*)(fp + k0 + 28);
            }

            const int kl = sg * 16;
            SUBL(wb, fA, kl + 0)
            SUBL(wb, fB, kl + 4)
            SUBL(wb, fC, kl + 8)
            SUBL(wb, fD, kl + 12)

            fA = nA; fB = nB; fC = nC; fD = nD;
        }

        // barrier: all waves done reading wbuf[ch&1] before iteration ch+1
        // stages into wbuf[(ch+2)&1] == wbuf[ch&1].
        __syncthreads();
    }
#undef SUBL
#undef STAGE_W

    float* eo = emit + (size_t)row * CTAGS + c0;
#pragma unroll
    for (int c = 0; c < 13; ++c) eo[c] = acc[c];
}

// ---------------------------------------------------------------------------
// K2: serial Viterbi scan (R7 champion, byte-identical logic).
// ---------------------------------------------------------------------------
#define CHUNK 32
#define CQ   (CHUNK * CTAGS / 4)   // float4s per chunk = 416

__global__ __launch_bounds__(64) void viterbi_scan(
    const float* __restrict__ emit, const int* __restrict__ masks,
    const float* __restrict__ T, float* __restrict__ s_hist,
    float* __restrict__ out, int* __restrict__ btag)
{
    const int b  = blockIdx.x;
    const int to = threadIdx.x;
    const int toc = (to < CTAGS) ? to : (CTAGS - 1);

    __shared__ float ebuf[2][CHUNK * CTAGS];     // 2 x 6656 B
    __shared__ int   ml[SEQL];                   // 2 KB
    __shared__ __align__(16) float st[64];       // state vector (52 used)

    const float4* Tq = (const float4*)(T + (size_t)toc * CTAGS);
    const float4 tr0 = Tq[0],  tr1 = Tq[1],  tr2 = Tq[2],  tr3 = Tq[3];
    const float4 tr4 = Tq[4],  tr5 = Tq[5],  tr6 = Tq[6],  tr7 = Tq[7];
    const float4 tr8 = Tq[8],  tr9 = Tq[9],  tr10 = Tq[10], tr11 = Tq[11];
    const float4 tr12 = Tq[12];
    const float tstop = T[STOP_IDX * CTAGS + toc];

    const float*  eb  = emit   + (size_t)b * SEQL * CTAGS;
    const float4* ebq = (const float4*)eb;
    const int*    mb  = masks  + (size_t)b * SEQL;
    float*        sb  = s_hist + (size_t)b * SEQL * CTAGS;

#pragma unroll
    for (int j = 0; j < 8; ++j) ml[to + 64 * j] = mb[to + 64 * j];
#pragma unroll
    for (int j = 0; j < 7; ++j) {
        int idx = to + 64 * j;
        if (idx < CQ) *(float4*)&ebuf[0][idx * 4] = ebq[idx];
    }
    st[to] = (to == START_IDX) ? 0.f : -10000.f;

    float cur   = (to == START_IDX) ? 0.f : -10000.f;
    float e_cur = ebuf[0][toc];
    int   m_cur = ml[0];
    int   cb    = 0;

    for (int c = 0; c < SEQL / CHUNK; ++c) {
        float4 p0, p1, p2, p3, p4, p5, p6;
        const int more = (c < SEQL / CHUNK - 1);
        if (more) {
            const float4* src = ebq + (size_t)(c + 1) * CQ;
            p0 = src[to];
            p1 = src[to + 64];
            p2 = src[to + 128];
            p3 = src[to + 192];
            p4 = src[to + 256];
            p5 = src[to + 320];
            if (to < CQ - 384) p6 = src[to + 384];
        }

        for (int s = 0; s < CHUNK; ++s) {
            const int t = c * CHUNK + s;

            float e_nxt = 0.f;
            if (s < CHUNK - 1) e_nxt = ebuf[cb][(s + 1) * CTAGS + toc];
            int m_nxt = (t + 1 < SEQL) ? ml[t + 1] : 0;

            if (to < CTAGS) sb[(size_t)t * CTAGS + to] = cur;

            const float4 s0q  = *(const float4*)&st[0];
            const float4 s1q  = *(const float4*)&st[4];
            const float4 s2q  = *(const float4*)&st[8];
            const float4 s3q  = *(const float4*)&st[12];
            const float4 s4q  = *(const float4*)&st[16];
            const float4 s5q  = *(const float4*)&st[20];
            const float4 s6q  = *(const float4*)&st[24];
            const float4 s7q  = *(const float4*)&st[28];
            const float4 s8q  = *(const float4*)&st[32];
            const float4 s9q  = *(const float4*)&st[36];
            const float4 s10q = *(const float4*)&st[40];
            const float4 s11q = *(const float4*)&st[44];
            const float4 s12q = *(const float4*)&st[48];

            float a[CTAGS];
#define ADQ(q, sq, trq)                                                      \
            a[4*q+0] = sq.x + trq.x;  a[4*q+1] = sq.y + trq.y;               \
            a[4*q+2] = sq.z + trq.z;  a[4*q+3] = sq.w + trq.w;
            ADQ(0, s0q, tr0)   ADQ(1, s1q, tr1)   ADQ(2, s2q, tr2)
            ADQ(3, s3q, tr3)   ADQ(4, s4q, tr4)   ADQ(5, s5q, tr5)
            ADQ(6, s6q, tr6)   ADQ(7, s7q, tr7)   ADQ(8, s8q, tr8)
            ADQ(9, s9q, tr9)   ADQ(10, s10q, tr10) ADQ(11, s11q, tr11)
            ADQ(12, s12q, tr12)
#undef ADQ

            float l1[17];
#pragma unroll
            for (int i = 0; i < 17; ++i)
                l1[i] = fmaxf(fmaxf(a[3 * i], a[3 * i + 1]), a[3 * i + 2]);
            float l2[6];
#pragma unroll
            for (int i = 0; i < 5; ++i)
                l2[i] = fmaxf(fmaxf(l1[3 * i], l1[3 * i + 1]), l1[3 * i + 2]);
            l2[5] = fmaxf(fmaxf(l1[15], l1[16]), a[51]);
            const float m = fmaxf(fmaxf(fmaxf(l2[0], l2[1]), l2[2]),
                                  fmaxf(fmaxf(l2[3], l2[4]), l2[5]));

            cur = m_cur ? (m + e_cur) : cur;

            if (to < CTAGS) st[to] = cur;

            e_cur = e_nxt;
            m_cur = m_nxt;
        }

        if (more) {
            const int nb = cb ^ 1;
            *(float4*)&ebuf[nb][to * 4]         = p0;
            *(float4*)&ebuf[nb][(to + 64) * 4]  = p1;
            *(float4*)&ebuf[nb][(to + 128) * 4] = p2;
            *(float4*)&ebuf[nb][(to + 192) * 4] = p3;
            *(float4*)&ebuf[nb][(to + 256) * 4] = p4;
            *(float4*)&ebuf[nb][(to + 320) * 4] = p5;
            if (to < CQ - 384) *(float4*)&ebuf[nb][(to + 384) * 4] = p6;
            e_cur = ebuf[nb][toc];
        }
        cb ^= 1;
    }

    float v   = (to < CTAGS) ? (cur + tstop) : NEG_INF;
    int  bidx = to;
#pragma unroll
    for (int s = 1; s < 64; s <<= 1) {
        float ov = __shfl_xor(v, s);
        int   oi = __shfl_xor(bidx, s);
        if (ov > v || (ov == v && oi < bidx)) { v = ov; bidx = oi; }
    }
    if (to == 0) { out[b] = v; btag[b] = bidx; }
}

// ---------------------------------------------------------------------------
// K3: backpointers, parallel over (b,t). (unchanged, known-good)
// ---------------------------------------------------------------------------
#define PPW 16

__global__ __launch_bounds__(256) void bp_compute(
    const float* __restrict__ s_hist, const float* __restrict__ T,
    unsigned char* __restrict__ bp)
{
    const int lane = threadIdx.x & 63;
    const int wv   = __builtin_amdgcn_readfirstlane(threadIdx.x >> 6);
    const int toc  = (lane < CTAGS) ? lane : (CTAGS - 1);
    const int w    = blockIdx.x * 4 + wv;

    float Trow[CTAGS];
#pragma unroll
    for (int f = 0; f < CTAGS; ++f) Trow[f] = T[toc * CTAGS + f];

    for (int i = 0; i < PPW; ++i) {
        const int p = w * PPW + i;            // p = b*SEQL + t
        const float* sp = s_hist + (size_t)p * CTAGS;

        float a[CTAGS];
#pragma unroll
        for (int q = 0; q < 13; ++q) {
            float4 sv = *(const float4*)(sp + q * 4);
            a[q * 4 + 0] = sv.x + Trow[q * 4 + 0];
            a[q * 4 + 1] = sv.y + Trow[q * 4 + 1];
            a[q * 4 + 2] = sv.z + Trow[q * 4 + 2];
            a[q * 4 + 3] = sv.w + Trow[q * 4 + 3];
        }

        float l1[17];
#pragma unroll
        for (int j = 0; j < 17; ++j)
            l1[j] = fmaxf(fmaxf(a[3 * j], a[3 * j + 1]), a[3 * j + 2]);
        float l2[6];
#pragma unroll
        for (int j = 0; j < 5; ++j)
            l2[j] = fmaxf(fmaxf(l1[3 * j], l1[3 * j + 1]), l1[3 * j + 2]);
        l2[5] = fmaxf(fmaxf(l1[15], l1[16]), a[51]);
        const float m = fmaxf(fmaxf(fmaxf(l2[0], l2[1]), l2[2]),
                              fmaxf(fmaxf(l2[3], l2[4]), l2[5]));

        int c1[18];
#pragma unroll
        for (int j = 0; j < 17; ++j) {
            int x = (a[3 * j]     == m) ? (3 * j)     : 63;
            int y = (a[3 * j + 1] == m) ? (3 * j + 1) : 63;
            int z = (a[3 * j + 2] == m) ? (3 * j + 2) : 63;
            c1[j] = min(min(x, y), z);
        }
        c1[17] = (a[51] == m) ? 51 : 63;
        int c2[6];
#pragma unroll
        for (int j = 0; j < 6; ++j)
            c2[j] = min(min(c1[3 * j], c1[3 * j + 1]), c1[3 * j + 2]);
        const int idx = min(min(min(c2[0], c2[1]), c2[2]),
                            min(min(c2[3], c2[4]), c2[5]));

        if (lane < CTAGS)
            bp[(size_t)p * CTAGS + lane] = (unsigned char)idx;
    }
}

// ---------------------------------------------------------------------------
// K4: backtrack (unchanged, known-good).
// ---------------------------------------------------------------------------
__global__ __launch_bounds__(64) void viterbi_bt(
    const unsigned char* __restrict__ bp, const int* __restrict__ masks,
    const int* __restrict__ btag, float* __restrict__ out)
{
    const int b   = blockIdx.x;
    const int tid = threadIdx.x;

    __shared__ __align__(16) unsigned char bpl[SEQL * CTAGS];
    __shared__ int ml[SEQL];
    __shared__ unsigned char pathb[SEQL];

    const uint4* src = (const uint4*)(bp + (size_t)b * SEQL * CTAGS);
    for (int i = tid; i < SEQL * CTAGS / 16; i += 64)
        ((uint4*)bpl)[i] = src[i];
    for (int i = tid; i < SEQL; i += 64) ml[i] = masks[(size_t)b * SEQL + i];
    __syncthreads();

    int c = btag[b];
    if (tid == 0) pathb[SEQL - 1] = (unsigned char)c;
    for (int i = SEQL - 2; i >= 0; --i) {
        int nxt = bpl[(i + 1) * CTAGS + c];
        c = ml[i] ? nxt : c;
        if (tid == 0) pathb[i] = (unsigned char)c;
    }
    __syncthreads();

    float* po = out + BATCH + (size_t)b * SEQL;
#pragma unroll
    for (int i = 0; i < 8; ++i)
        po[i * 64 + tid] = (float)pathb[i * 64 + tid];
}

// ---------------------------------------------------------------------------
extern "C" void kernel_launch(void* const* d_in, const int* in_sizes, int n_in,
                              void* d_out, int out_size, void* d_ws, size_t ws_size,
                              hipStream_t stream)
{
    const float* features = (const float*)d_in[0];
    const int*   masks    = (const int*)d_in[1];
    const float* W        = (const float*)d_in[2];
    const float* bias     = (const float*)d_in[3];
    const float* T        = (const float*)d_in[4];

    float* out = (float*)d_out;

    // ws layout: emit/s_hist (13.63 MB, aliased) | bp (3.41 MB) | btag
    const size_t emit_bytes = (size_t)BATCH * SEQL * CTAGS * sizeof(float);
    const size_t bp_bytes   = (size_t)BATCH * SEQL * CTAGS;
    float*         emit   = (float*)d_ws;
    float*         s_hist = emit;  // alias: scan consumes emit[t] before overwrite
    unsigned char* bpws   = (unsigned char*)d_ws + emit_bytes;
    int*           btag   = (int*)((unsigned char*)d_ws + emit_bytes + bp_bytes);

    emit_gemm9<<<BATCH * SEQL / 64, 256, 0, stream>>>(features, W, bias, emit);
    viterbi_scan<<<BATCH, 64, 0, stream>>>(emit, masks, T, s_hist, out, btag);
    bp_compute<<<BATCH * SEQL / (4 * PPW), 256, 0, stream>>>(s_hist, T, bpws);
    viterbi_bt<<<BATCH, 64, 0, stream>>>(bpws, masks, btag, out);
}

// Round 15
// 325.763 us; speedup vs baseline: 8.4934x; 5.1367x over previous
//
#include <hip/hip_runtime.h>
#include <stdint.h>

#define BATCH 128
#define SEQL  512
#define FDIM  768
#define CTAGS 52
#define START_IDX 50
#define STOP_IDX  51
#define NEG_INF (-3.0e38f)

// ---------------------------------------------------------------------------
// K0: transpose W [52][768] -> WT [768][52]. Tiny, runs once.
// ---------------------------------------------------------------------------
__global__ __launch_bounds__(256) void wtrans(
    const float* __restrict__ W, float* __restrict__ WT)
{
    int idx = blockIdx.x * 256 + threadIdx.x;
    if (idx < FDIM * CTAGS) {
        int k = idx / CTAGS;
        int c = idx - k * CTAGS;
        WT[idx] = W[(size_t)c * FDIM + k];
    }
}

// ---------------------------------------------------------------------------
// K1: emission GEMM v10 — gemm6 (proven: W scalar path, F per-lane global
// dwordx4, no LDS, no barriers) with TWO row streams per lane: lane covers
// rows `row` and `row+64`. Each 4-k group's 52 scalar W floats now feed
// 104 FMAs (2x density) -> wave count halves (2048) -> scalar-cache traffic
// halves (160 -> 80 MB), which was the measured 130 us wall in gemm6.
// Grid 512 blocks = 2 blocks/CU, 2 waves/SIMD.
// ---------------------------------------------------------------------------
__global__ __launch_bounds__(256) void emit_gemm10(
    const float* __restrict__ F, const float* __restrict__ WT,
    const float* __restrict__ bias, float* __restrict__ emit)
{
    const int lane = threadIdx.x & 63;
    const int cg   = __builtin_amdgcn_readfirstlane(threadIdx.x >> 6);
    const int c0   = cg * 13;
    const int row  = blockIdx.x * 128 + lane;   // second row = row + 64

    const float* fp0 = F + (size_t)row * FDIM;
    const float* fp1 = fp0 + (size_t)64 * FDIM;

    float acc0[13], acc1[13];
#pragma unroll
    for (int c = 0; c < 13; ++c) { acc0[c] = bias[c0 + c]; acc1[c] = acc0[c]; }

    // 4-k sub-group: 13x4 uniform W floats (s_load), 104 FMAs (2 streams)
#define SUB2(f0q, f1q, kbase)                                                \
    {                                                                        \
        const float* w0 = WT + (size_t)((kbase) + 0) * CTAGS + c0;           \
        const float* w1 = WT + (size_t)((kbase) + 1) * CTAGS + c0;           \
        const float* w2 = WT + (size_t)((kbase) + 2) * CTAGS + c0;           \
        const float* w3 = WT + (size_t)((kbase) + 3) * CTAGS + c0;           \
        _Pragma("unroll")                                                    \
        for (int c = 0; c < 13; ++c) {                                       \
            float wa = w0[c], wb = w1[c], wc = w2[c], wd = w3[c];            \
            acc0[c] = fmaf(f0q.x, wa, acc0[c]);                              \
            acc0[c] = fmaf(f0q.y, wb, acc0[c]);                              \
            acc0[c] = fmaf(f0q.z, wc, acc0[c]);                              \
            acc0[c] = fmaf(f0q.w, wd, acc0[c]);                              \
            acc1[c] = fmaf(f1q.x, wa, acc1[c]);                              \
            acc1[c] = fmaf(f1q.y, wb, acc1[c]);                              \
            acc1[c] = fmaf(f1q.z, wc, acc1[c]);                              \
            acc1[c] = fmaf(f1q.w, wd, acc1[c]);                              \
        }                                                                    \
    }

    // prologue: first 16-k supergroup, both streams
    float4 a0 = *(const float4*)(fp0 + 0);
    float4 a1 = *(const float4*)(fp0 + 4);
    float4 a2 = *(const float4*)(fp0 + 8);
    float4 a3 = *(const float4*)(fp0 + 12);
    float4 b0 = *(const float4*)(fp1 + 0);
    float4 b1 = *(const float4*)(fp1 + 4);
    float4 b2 = *(const float4*)(fp1 + 8);
    float4 b3 = *(const float4*)(fp1 + 12);

    for (int k0 = 0; k0 < FDIM; k0 += 16) {
        // prefetch next supergroup (vmcnt pipe; consumed ~500 cyc later)
        float4 nA0, nA1, nA2, nA3, nB0, nB1, nB2, nB3;
        if (k0 + 16 < FDIM) {
            nA0 = *(const float4*)(fp0 + k0 + 16);
            nA1 = *(const float4*)(fp0 + k0 + 20);
            nA2 = *(const float4*)(fp0 + k0 + 24);
            nA3 = *(const float4*)(fp0 + k0 + 28);
            nB0 = *(const float4*)(fp1 + k0 + 16);
            nB1 = *(const float4*)(fp1 + k0 + 20);
            nB2 = *(const float4*)(fp1 + k0 + 24);
            nB3 = *(const float4*)(fp1 + k0 + 28);
        }

        SUB2(a0, b0, k0 + 0)
        SUB2(a1, b1, k0 + 4)
        SUB2(a2, b2, k0 + 8)
        SUB2(a3, b3, k0 + 12)

        a0 = nA0; a1 = nA1; a2 = nA2; a3 = nA3;
        b0 = nB0; b1 = nB1; b2 = nB2; b3 = nB3;
    }
#undef SUB2

    float* eo0 = emit + (size_t)row * CTAGS + c0;
    float* eo1 = emit + (size_t)(row + 64) * CTAGS + c0;
#pragma unroll
    for (int c = 0; c < 13; ++c) { eo0[c] = acc0[c]; eo1[c] = acc1[c]; }
}

// ---------------------------------------------------------------------------
// K2: serial Viterbi scan (R7 champion, byte-identical logic).
// ---------------------------------------------------------------------------
#define CHUNK 32
#define CQ   (CHUNK * CTAGS / 4)   // float4s per chunk = 416

__global__ __launch_bounds__(64) void viterbi_scan(
    const float* __restrict__ emit, const int* __restrict__ masks,
    const float* __restrict__ T, float* __restrict__ s_hist,
    float* __restrict__ out, int* __restrict__ btag)
{
    const int b  = blockIdx.x;
    const int to = threadIdx.x;
    const int toc = (to < CTAGS) ? to : (CTAGS - 1);

    __shared__ float ebuf[2][CHUNK * CTAGS];     // 2 x 6656 B
    __shared__ int   ml[SEQL];                   // 2 KB
    __shared__ __align__(16) float st[64];       // state vector (52 used)

    const float4* Tq = (const float4*)(T + (size_t)toc * CTAGS);
    const float4 tr0 = Tq[0],  tr1 = Tq[1],  tr2 = Tq[2],  tr3 = Tq[3];
    const float4 tr4 = Tq[4],  tr5 = Tq[5],  tr6 = Tq[6],  tr7 = Tq[7];
    const float4 tr8 = Tq[8],  tr9 = Tq[9],  tr10 = Tq[10], tr11 = Tq[11];
    const float4 tr12 = Tq[12];
    const float tstop = T[STOP_IDX * CTAGS + toc];

    const float*  eb  = emit   + (size_t)b * SEQL * CTAGS;
    const float4* ebq = (const float4*)eb;
    const int*    mb  = masks  + (size_t)b * SEQL;
    float*        sb  = s_hist + (size_t)b * SEQL * CTAGS;

#pragma unroll
    for (int j = 0; j < 8; ++j) ml[to + 64 * j] = mb[to + 64 * j];
#pragma unroll
    for (int j = 0; j < 7; ++j) {
        int idx = to + 64 * j;
        if (idx < CQ) *(float4*)&ebuf[0][idx * 4] = ebq[idx];
    }
    st[to] = (to == START_IDX) ? 0.f : -10000.f;

    float cur   = (to == START_IDX) ? 0.f : -10000.f;
    float e_cur = ebuf[0][toc];
    int   m_cur = ml[0];
    int   cb    = 0;

    for (int c = 0; c < SEQL / CHUNK; ++c) {
        float4 p0, p1, p2, p3, p4, p5, p6;
        const int more = (c < SEQL / CHUNK - 1);
        if (more) {
            const float4* src = ebq + (size_t)(c + 1) * CQ;
            p0 = src[to];
            p1 = src[to + 64];
            p2 = src[to + 128];
            p3 = src[to + 192];
            p4 = src[to + 256];
            p5 = src[to + 320];
            if (to < CQ - 384) p6 = src[to + 384];
        }

        for (int s = 0; s < CHUNK; ++s) {
            const int t = c * CHUNK + s;

            float e_nxt = 0.f;
            if (s < CHUNK - 1) e_nxt = ebuf[cb][(s + 1) * CTAGS + toc];
            int m_nxt = (t + 1 < SEQL) ? ml[t + 1] : 0;

            if (to < CTAGS) sb[(size_t)t * CTAGS + to] = cur;

            const float4 s0q  = *(const float4*)&st[0];
            const float4 s1q  = *(const float4*)&st[4];
            const float4 s2q  = *(const float4*)&st[8];
            const float4 s3q  = *(const float4*)&st[12];
            const float4 s4q  = *(const float4*)&st[16];
            const float4 s5q  = *(const float4*)&st[20];
            const float4 s6q  = *(const float4*)&st[24];
            const float4 s7q  = *(const float4*)&st[28];
            const float4 s8q  = *(const float4*)&st[32];
            const float4 s9q  = *(const float4*)&st[36];
            const float4 s10q = *(const float4*)&st[40];
            const float4 s11q = *(const float4*)&st[44];
            const float4 s12q = *(const float4*)&st[48];

            float a[CTAGS];
#define ADQ(q, sq, trq)                                                      \
            a[4*q+0] = sq.x + trq.x;  a[4*q+1] = sq.y + trq.y;               \
            a[4*q+2] = sq.z + trq.z;  a[4*q+3] = sq.w + trq.w;
            ADQ(0, s0q, tr0)   ADQ(1, s1q, tr1)   ADQ(2, s2q, tr2)
            ADQ(3, s3q, tr3)   ADQ(4, s4q, tr4)   ADQ(5, s5q, tr5)
            ADQ(6, s6q, tr6)   ADQ(7, s7q, tr7)   ADQ(8, s8q, tr8)
            ADQ(9, s9q, tr9)   ADQ(10, s10q, tr10) ADQ(11, s11q, tr11)
            ADQ(12, s12q, tr12)
#undef ADQ

            float l1[17];
#pragma unroll
            for (int i = 0; i < 17; ++i)
                l1[i] = fmaxf(fmaxf(a[3 * i], a[3 * i + 1]), a[3 * i + 2]);
            float l2[6];
#pragma unroll
            for (int i = 0; i < 5; ++i)
                l2[i] = fmaxf(fmaxf(l1[3 * i], l1[3 * i + 1]), l1[3 * i + 2]);
            l2[5] = fmaxf(fmaxf(l1[15], l1[16]), a[51]);
            const float m = fmaxf(fmaxf(fmaxf(l2[0], l2[1]), l2[2]),
                                  fmaxf(fmaxf(l2[3], l2[4]), l2[5]));

            cur = m_cur ? (m + e_cur) : cur;

            if (to < CTAGS) st[to] = cur;

            e_cur = e_nxt;
            m_cur = m_nxt;
        }

        if (more) {
            const int nb = cb ^ 1;
            *(float4*)&ebuf[nb][to * 4]         = p0;
            *(float4*)&ebuf[nb][(to + 64) * 4]  = p1;
            *(float4*)&ebuf[nb][(to + 128) * 4] = p2;
            *(float4*)&ebuf[nb][(to + 192) * 4] = p3;
            *(float4*)&ebuf[nb][(to + 256) * 4] = p4;
            *(float4*)&ebuf[nb][(to + 320) * 4] = p5;
            if (to < CQ - 384) *(float4*)&ebuf[nb][(to + 384) * 4] = p6;
            e_cur = ebuf[nb][toc];
        }
        cb ^= 1;
    }

    float v   = (to < CTAGS) ? (cur + tstop) : NEG_INF;
    int  bidx = to;
#pragma unroll
    for (int s = 1; s < 64; s <<= 1) {
        float ov = __shfl_xor(v, s);
        int   oi = __shfl_xor(bidx, s);
        if (ov > v || (ov == v && oi < bidx)) { v = ov; bidx = oi; }
    }
    if (to == 0) { out[b] = v; btag[b] = bidx; }
}

// ---------------------------------------------------------------------------
// K3: backpointers, parallel over (b,t). (unchanged, known-good)
// ---------------------------------------------------------------------------
#define PPW 16

__global__ __launch_bounds__(256) void bp_compute(
    const float* __restrict__ s_hist, const float* __restrict__ T,
    unsigned char* __restrict__ bp)
{
    const int lane = threadIdx.x & 63;
    const int wv   = __builtin_amdgcn_readfirstlane(threadIdx.x >> 6);
    const int toc  = (lane < CTAGS) ? lane : (CTAGS - 1);
    const int w    = blockIdx.x * 4 + wv;

    float Trow[CTAGS];
#pragma unroll
    for (int f = 0; f < CTAGS; ++f) Trow[f] = T[toc * CTAGS + f];

    for (int i = 0; i < PPW; ++i) {
        const int p = w * PPW + i;            // p = b*SEQL + t
        const float* sp = s_hist + (size_t)p * CTAGS;

        float a[CTAGS];
#pragma unroll
        for (int q = 0; q < 13; ++q) {
            float4 sv = *(const float4*)(sp + q * 4);
            a[q * 4 + 0] = sv.x + Trow[q * 4 + 0];
            a[q * 4 + 1] = sv.y + Trow[q * 4 + 1];
            a[q * 4 + 2] = sv.z + Trow[q * 4 + 2];
            a[q * 4 + 3] = sv.w + Trow[q * 4 + 3];
        }

        float l1[17];
#pragma unroll
        for (int j = 0; j < 17; ++j)
            l1[j] = fmaxf(fmaxf(a[3 * j], a[3 * j + 1]), a[3 * j + 2]);
        float l2[6];
#pragma unroll
        for (int j = 0; j < 5; ++j)
            l2[j] = fmaxf(fmaxf(l1[3 * j], l1[3 * j + 1]), l1[3 * j + 2]);
        l2[5] = fmaxf(fmaxf(l1[15], l1[16]), a[51]);
        const float m = fmaxf(fmaxf(fmaxf(l2[0], l2[1]), l2[2]),
                              fmaxf(fmaxf(l2[3], l2[4]), l2[5]));

        int c1[18];
#pragma unroll
        for (int j = 0; j < 17; ++j) {
            int x = (a[3 * j]     == m) ? (3 * j)     : 63;
            int y = (a[3 * j + 1] == m) ? (3 * j + 1) : 63;
            int z = (a[3 * j + 2] == m) ? (3 * j + 2) : 63;
            c1[j] = min(min(x, y), z);
        }
        c1[17] = (a[51] == m) ? 51 : 63;
        int c2[6];
#pragma unroll
        for (int j = 0; j < 6; ++j)
            c2[j] = min(min(c1[3 * j], c1[3 * j + 1]), c1[3 * j + 2]);
        const int idx = min(min(min(c2[0], c2[1]), c2[2]),
                            min(min(c2[3], c2[4]), c2[5]));

        if (lane < CTAGS)
            bp[(size_t)p * CTAGS + lane] = (unsigned char)idx;
    }
}

// ---------------------------------------------------------------------------
// K4: backtrack (unchanged, known-good).
// ---------------------------------------------------------------------------
__global__ __launch_bounds__(64) void viterbi_bt(
    const unsigned char* __restrict__ bp, const int* __restrict__ masks,
    const int* __restrict__ btag, float* __restrict__ out)
{
    const int b   = blockIdx.x;
    const int tid = threadIdx.x;

    __shared__ __align__(16) unsigned char bpl[SEQL * CTAGS];
    __shared__ int ml[SEQL];
    __shared__ unsigned char pathb[SEQL];

    const uint4* src = (const uint4*)(bp + (size_t)b * SEQL * CTAGS);
    for (int i = tid; i < SEQL * CTAGS / 16; i += 64)
        ((uint4*)bpl)[i] = src[i];
    for (int i = tid; i < SEQL; i += 64) ml[i] = masks[(size_t)b * SEQL + i];
    __syncthreads();

    int c = btag[b];
    if (tid == 0) pathb[SEQL - 1] = (unsigned char)c;
    for (int i = SEQL - 2; i >= 0; --i) {
        int nxt = bpl[(i + 1) * CTAGS + c];
        c = ml[i] ? nxt : c;
        if (tid == 0) pathb[i] = (unsigned char)c;
    }
    __syncthreads();

    float* po = out + BATCH + (size_t)b * SEQL;
#pragma unroll
    for (int i = 0; i < 8; ++i)
        po[i * 64 + tid] = (float)pathb[i * 64 + tid];
}

// ---------------------------------------------------------------------------
extern "C" void kernel_launch(void* const* d_in, const int* in_sizes, int n_in,
                              void* d_out, int out_size, void* d_ws, size_t ws_size,
                              hipStream_t stream)
{
    const float* features = (const float*)d_in[0];
    const int*   masks    = (const int*)d_in[1];
    const float* W        = (const float*)d_in[2];
    const float* bias     = (const float*)d_in[3];
    const float* T        = (const float*)d_in[4];

    float* out = (float*)d_out;

    // ws layout: emit/s_hist (13.63 MB, aliased) | bp (3.41 MB) | btag
    // WT (160 KB) aliases the bp region: dead before bp_compute writes.
    const size_t emit_bytes = (size_t)BATCH * SEQL * CTAGS * sizeof(float);
    const size_t bp_bytes   = (size_t)BATCH * SEQL * CTAGS;
    float*         emit   = (float*)d_ws;
    float*         s_hist = emit;  // alias: scan consumes emit[t] before overwrite
    unsigned char* bpws   = (unsigned char*)d_ws + emit_bytes;
    float*         WT     = (float*)bpws;
    int*           btag   = (int*)((unsigned char*)d_ws + emit_bytes + bp_bytes);

    wtrans<<<(FDIM * CTAGS + 255) / 256, 256, 0, stream>>>(W, WT);
    emit_gemm10<<<BATCH * SEQL / 128, 256, 0, stream>>>(features, WT, bias, emit);
    viterbi_scan<<<BATCH, 64, 0, stream>>>(emit, masks, T, s_hist, out, btag);
    bp_compute<<<BATCH * SEQL / (4 * PPW), 256, 0, stream>>>(s_hist, T, bpws);
    viterbi_bt<<<BATCH, 64, 0, stream>>>(bpws, masks, btag, out);
}